// Round 1
// baseline (2041.396 us; speedup 1.0000x reference)
//
#include <hip/hip_runtime.h>
#include <hip/hip_bf16.h>

// ---------------------------------------------------------------------------
// PCELayer: router(softmax over fourier feats) + 8 expert conv3x3+GN+SiLU+res,
// weighted merge, merge GN+SiLU gamma-residual, post conv3x3+GN+SiLU.
// Convs run as implicit GEMM on bf16 MFMA (M=pixels, N=cout, K=9*cin).
// ---------------------------------------------------------------------------

typedef __attribute__((ext_vector_type(8))) short bf16x8;
typedef __attribute__((ext_vector_type(4))) float f32x4;
typedef __attribute__((ext_vector_type(8))) unsigned short u16x8;

__device__ __forceinline__ float b2f(unsigned short u) {
  unsigned int v = ((unsigned int)u) << 16;
  return __builtin_bit_cast(float, v);
}
__device__ __forceinline__ unsigned short f2b(float f) {
  __hip_bfloat16 h = __float2bfloat16(f);
  return __builtin_bit_cast(unsigned short, h);
}
__device__ __forceinline__ float silu_f(float x) {
  return x / (1.f + __expf(-x));
}
__device__ __forceinline__ void gll16(const void* g, void* l) {
  __builtin_amdgcn_global_load_lds(
      (const __attribute__((address_space(1))) unsigned int*)g,
      (__attribute__((address_space(3))) unsigned int*)l, 16, 0, 0);
}

// ---- router: 64 patches x 8 experts -------------------------------------
__global__ void k_router(const float* __restrict__ rw, const float* __restrict__ rb,
                         float* __restrict__ wts) {
  int t = threadIdx.x;
  if (t >= 64) return;
  int py = t >> 3, px = t & 7;
  float cy = (py + 0.5f) / 8.f, cx = (px + 0.5f) / 8.f;
  const float PI = 3.14159265358979323846f;
  float f[16];
#pragma unroll
  for (int k = 0; k < 4; ++k) {
    float fr = (float)(1 << k) * PI;
    f[k]      = sinf(cy * fr);
    f[4 + k]  = cosf(cy * fr);
    f[8 + k]  = sinf(cx * fr);
    f[12 + k] = cosf(cx * fr);
  }
  float lg[8], mx = -1e30f;
#pragma unroll
  for (int e = 0; e < 8; ++e) {
    float a = rb[e];
#pragma unroll
    for (int k = 0; k < 16; ++k) a += f[k] * rw[k * 8 + e];
    lg[e] = a; mx = fmaxf(mx, a);
  }
  float s = 0.f;
#pragma unroll
  for (int e = 0; e < 8; ++e) { lg[e] = __expf(lg[e] - mx); s += lg[e]; }
  float inv = 1.f / s;
#pragma unroll
  for (int e = 0; e < 8; ++e) wts[t * 8 + e] = lg[e] * inv;
}

// ---- x (NCHW f32) -> padded NHWC bf16 [8][130][130][128] ------------------
__global__ void k_build_xpad(const float* __restrict__ x, __hip_bfloat16* __restrict__ xp) {
  int bx = blockIdx.x;
  int wb = bx & 1, cib = (bx >> 1) & 1;
  int h = (bx >> 2) & 127, b = bx >> 9;
  int w0 = wb * 64, ci0 = cib * 64;
  __shared__ float t[64][65];
  int tid = threadIdx.x;
#pragma unroll
  for (int r = 0; r < 16; ++r) {
    int idx = r * 256 + tid;
    int i = idx >> 6, j = idx & 63;  // i: ci, j: w
    t[i][j] = x[(((size_t)b * 128 + ci0 + i) * 128 + h) * 128 + w0 + j];
  }
  __syncthreads();
  unsigned short* xpu = (unsigned short*)xp;
#pragma unroll
  for (int r = 0; r < 16; ++r) {
    int idx = r * 256 + tid;
    int j = idx >> 6, i = idx & 63;  // j: w, i: ci
    xpu[(((size_t)b * 130 + h + 1) * 130 + (w0 + j + 1)) * 128 + ci0 + i] = f2b(t[i][j]);
  }
}

// ---- weights [e][co][ci][3][3] f32 -> [e][tap][co][ci] bf16 ---------------
__global__ void k_build_w(const float* __restrict__ src, __hip_bfloat16* __restrict__ dst,
                          int total) {
  int o = blockIdx.x * 256 + threadIdx.x;
  if (o >= total) return;
  int ci = o & 127, co = (o >> 7) & 127;
  int r = o >> 14; int tp = r % 9, e = r / 9;
  ((unsigned short*)dst)[o] =
      f2b(src[(((size_t)e * 128 + co) * 128 + ci) * 9 + tp]);
}

// ---- conv3x3 as implicit GEMM: 128 pixels (one b,h row) x 128 cout --------
// K = 9 taps x 4 chunks of 32 cin.  Double-buffered LDS, global_load_lds x16,
// XOR quarter-swizzle applied on global source + ds_read (G21).
__global__ __launch_bounds__(256, 2) void k_conv(
    const __hip_bfloat16* __restrict__ xp, const __hip_bfloat16* __restrict__ wt,
    __hip_bfloat16* __restrict__ outb, float* __restrict__ stats) {
  __shared__ __align__(16) char smem[2][2][8192];  // [buf][A/B][bytes]
  const int bx = blockIdx.x;
  const int b = bx >> 7, h = bx & 127;
  const int tid = threadIdx.x;
  const int lane = tid & 63;
  const int wid = tid >> 6;
  const int wave_m = wid >> 1, wave_n = wid & 1;
  const int rl = lane & 15, kg = lane >> 4;
  const int qsw = (kg ^ ((rl >> 1) & 3)) * 16;

  f32x4 acc[4][4] = {};
  const unsigned short* xpu = (const unsigned short*)xp;
  const unsigned short* wtu = (const unsigned short*)wt;

  auto stage = [&](int bufi, int kk) {
    const int tp = kk >> 2, cc = kk & 3;
    const int ky = tp / 3, kx = tp - ky * 3;
    const size_t arow = ((size_t)(b * 130 + h + ky)) * 130;
#pragma unroll
    for (int g2 = 0; g2 < 2; ++g2) {
      int s = g2 * 256 + tid;
      int p = s >> 2, q = s & 3;
      int qg = q ^ ((p >> 1) & 3);
      const unsigned short* src = xpu + (arow + (p + kx)) * 128 + cc * 32 + qg * 8;
      gll16(src, &smem[bufi][0][s * 16]);
    }
#pragma unroll
    for (int g2 = 0; g2 < 2; ++g2) {
      int s = g2 * 256 + tid;
      int p = s >> 2, q = s & 3;
      int qg = q ^ ((p >> 1) & 3);
      const unsigned short* src = wtu + ((size_t)(tp * 128 + p)) * 128 + cc * 32 + qg * 8;
      gll16(src, &smem[bufi][1][s * 16]);
    }
  };

  stage(0, 0);
#pragma unroll 2
  for (int kk = 0; kk < 36; ++kk) {
    const int bufi = kk & 1;
    __syncthreads();
    if (kk + 1 < 36) stage(bufi ^ 1, kk + 1);
    bf16x8 aF[4], bF[4];
#pragma unroll
    for (int mb = 0; mb < 4; ++mb)
      aF[mb] = *(const bf16x8*)&smem[bufi][0][(wave_m * 64 + mb * 16 + rl) * 64 + qsw];
#pragma unroll
    for (int nb = 0; nb < 4; ++nb)
      bF[nb] = *(const bf16x8*)&smem[bufi][1][(wave_n * 64 + nb * 16 + rl) * 64 + qsw];
#pragma unroll
    for (int mb = 0; mb < 4; ++mb)
#pragma unroll
      for (int nb = 0; nb < 4; ++nb)
        acc[mb][nb] = __builtin_amdgcn_mfma_f32_16x16x32_bf16(aF[mb], bF[nb], acc[mb][nb], 0, 0, 0);
  }

  // epilogue: store bf16 NHWC + GN partial sums (per 16-ch group) via atomics
  const int row0 = (lane >> 4) * 4;
  const int colL = lane & 15;
  float sv[4] = {0, 0, 0, 0}, qv[4] = {0, 0, 0, 0};
  unsigned short* outu = (unsigned short*)outb;
#pragma unroll
  for (int mb = 0; mb < 4; ++mb) {
#pragma unroll
    for (int nb = 0; nb < 4; ++nb) {
      const int co = wave_n * 64 + nb * 16 + colL;
#pragma unroll
      for (int j = 0; j < 4; ++j) {
        const int w = wave_m * 64 + mb * 16 + row0 + j;
        float v = acc[mb][nb][j];
        outu[(((size_t)b * 128 + h) * 128 + w) * 128 + co] = f2b(v);
        sv[nb] += v; qv[nb] += v * v;
      }
    }
  }
#pragma unroll
  for (int nb = 0; nb < 4; ++nb) {
    float a = sv[nb], q = qv[nb];
#pragma unroll
    for (int o = 32; o > 0; o >>= 1) { a += __shfl_down(a, o); q += __shfl_down(q, o); }
    if (lane == 0) {
      const int g = wave_n * 4 + nb;
      atomicAdd(&stats[(b * 8 + g) * 2 + 0], a);
      atomicAdd(&stats[(b * 8 + g) * 2 + 1], q);
    }
  }
}

// ---- merge accumulate: merged += w_e * silu(gn_e(conv_e)) -----------------
__global__ void k_merge(const __hip_bfloat16* __restrict__ conv, const float* __restrict__ st,
                        const float* __restrict__ gam, const float* __restrict__ bet,
                        const float* __restrict__ wts, float* __restrict__ merged,
                        int e, int accum) {
  size_t idx = ((size_t)blockIdx.x * 256 + threadIdx.x) * 8;
  int co0 = (int)(idx & 127);
  size_t pix = idx >> 7;
  int w = (int)(pix & 127), h = (int)((pix >> 7) & 127), b = (int)(pix >> 14);
  int g = co0 >> 4;
  const float cnt = 16.f * 128.f * 128.f;
  float mean = st[(b * 8 + g) * 2] / cnt;
  float var = st[(b * 8 + g) * 2 + 1] / cnt - mean * mean;
  float rstd = rsqrtf(var + 1e-5f);
  float we = wts[(((h >> 4) * 8) + (w >> 4)) * 8 + e];
  u16x8 cv = *(const u16x8*)((const unsigned short*)conv + idx);
  f32x4 m0, m1;
  if (accum) {
    m0 = *(const f32x4*)(merged + idx);
    m1 = *(const f32x4*)(merged + idx + 4);
  } else {
    m0 = (f32x4)0.f; m1 = (f32x4)0.f;
  }
#pragma unroll
  for (int i = 0; i < 8; ++i) {
    float v = b2f(cv[i]);
    float xn = (v - mean) * rstd * gam[co0 + i] + bet[co0 + i];
    float add = we * silu_f(xn);
    if (i < 4) m0[i] += add; else m1[i - 4] += add;
  }
  *(f32x4*)(merged + idx) = m0;
  *(f32x4*)(merged + idx + 4) = m1;
}

// ---- stats of M = merged + x (per b,group) --------------------------------
__global__ void k_stats2(const float* __restrict__ merged, const __hip_bfloat16* __restrict__ xp,
                         float* __restrict__ st) {
  __shared__ float sg[16];
  int tid = threadIdx.x;
  if (tid < 16) sg[tid] = 0.f;
  __syncthreads();
  size_t idx = ((size_t)blockIdx.x * 256 + tid) * 8;
  int co0 = (int)(idx & 127);
  size_t pix = idx >> 7;
  int w = (int)(pix & 127), h = (int)((pix >> 7) & 127), b = (int)(pix >> 14);
  int g = co0 >> 4;
  const unsigned short* xr =
      (const unsigned short*)xp + (((size_t)b * 130 + h + 1) * 130 + (w + 1)) * 128 + co0;
  u16x8 xv = *(const u16x8*)xr;
  f32x4 m0 = *(const f32x4*)(merged + idx), m1 = *(const f32x4*)(merged + idx + 4);
  float s = 0.f, q = 0.f;
#pragma unroll
  for (int i = 0; i < 8; ++i) {
    float M = ((i < 4) ? m0[i] : m1[i - 4]) + b2f(xv[i]);
    s += M; q += M * M;
  }
  atomicAdd(&sg[g * 2 + 0], s);
  atomicAdd(&sg[g * 2 + 1], q);
  __syncthreads();
  if (tid < 16) atomicAdd(&st[b * 16 + tid], sg[tid]);
}

// ---- y = x + gamma*silu(gn(M)); write bf16 into padded buffer (in place) --
__global__ void k_ypass(const float* __restrict__ merged, __hip_bfloat16* __restrict__ xp,
                        const float* __restrict__ st, const float* __restrict__ mg,
                        const float* __restrict__ mbv, const float* __restrict__ gptr) {
  size_t idx = ((size_t)blockIdx.x * 256 + threadIdx.x) * 8;
  int co0 = (int)(idx & 127);
  size_t pix = idx >> 7;
  int w = (int)(pix & 127), h = (int)((pix >> 7) & 127), b = (int)(pix >> 14);
  int g = co0 >> 4;
  const float cnt = 16.f * 128.f * 128.f;
  float mean = st[(b * 8 + g) * 2] / cnt;
  float var = st[(b * 8 + g) * 2 + 1] / cnt - mean * mean;
  float rstd = rsqrtf(var + 1e-5f);
  float gm = gptr[0];
  unsigned short* xr =
      (unsigned short*)xp + (((size_t)b * 130 + h + 1) * 130 + (w + 1)) * 128 + co0;
  u16x8 xv = *(const u16x8*)xr;
  f32x4 m0 = *(const f32x4*)(merged + idx), m1 = *(const f32x4*)(merged + idx + 4);
  u16x8 yv;
#pragma unroll
  for (int i = 0; i < 8; ++i) {
    float xf = b2f(xv[i]);
    float M = ((i < 4) ? m0[i] : m1[i - 4]) + xf;
    float xn = (M - mean) * rstd * mg[co0 + i] + mbv[co0 + i];
    yv[i] = f2b(xf + gm * silu_f(xn));
  }
  *(u16x8*)xr = yv;
}

// ---- final: out = silu(gn3(conv3)), NHWC bf16 -> NCHW f32 via LDS transpose
__global__ void k_final(const __hip_bfloat16* __restrict__ conv, const float* __restrict__ st,
                        const float* __restrict__ pg, const float* __restrict__ pb,
                        float* __restrict__ out) {
  int bx = blockIdx.x;
  int wb = bx & 1, h = (bx >> 1) & 127, b = bx >> 8;
  int w0 = wb * 64;
  __shared__ float t[64][129];
  int tid = threadIdx.x;
  const float cnt = 16.f * 128.f * 128.f;
  const unsigned short* cu = (const unsigned short*)conv;
#pragma unroll
  for (int r = 0; r < 32; ++r) {
    int e2 = r * 256 + tid;
    int co = e2 & 127, wl = e2 >> 7;
    int g = co >> 4;
    float mean = st[(b * 8 + g) * 2] / cnt;
    float var = st[(b * 8 + g) * 2 + 1] / cnt - mean * mean;
    float rstd = rsqrtf(var + 1e-5f);
    float v = b2f(cu[(((size_t)b * 128 + h) * 128 + w0 + wl) * 128 + co]);
    float xn = (v - mean) * rstd * pg[co] + pb[co];
    t[wl][co] = silu_f(xn);
  }
  __syncthreads();
#pragma unroll
  for (int r = 0; r < 8; ++r) {
    int f = r * 256 + tid;
    int jb = f & 15, co = f >> 4;
    f32x4 o;
#pragma unroll
    for (int j = 0; j < 4; ++j) o[j] = t[jb * 4 + j][co];
    *(f32x4*)&out[(((size_t)b * 128 + co) * 128 + h) * 128 + w0 + jb * 4] = o;
  }
}

// ---------------------------------------------------------------------------
extern "C" void kernel_launch(void* const* d_in, const int* in_sizes, int n_in,
                              void* d_out, int out_size, void* d_ws, size_t ws_size,
                              hipStream_t stream) {
  const float* x        = (const float*)d_in[0];
  const float* expert_w = (const float*)d_in[1];
  const float* expert_g = (const float*)d_in[2];
  const float* expert_b = (const float*)d_in[3];
  const float* router_w = (const float*)d_in[4];
  const float* router_b = (const float*)d_in[5];
  const float* merge_g  = (const float*)d_in[6];
  const float* merge_b  = (const float*)d_in[7];
  const float* gamma    = (const float*)d_in[8];
  const float* post_w   = (const float*)d_in[9];
  const float* post_g   = (const float*)d_in[10];
  const float* post_b   = (const float*)d_in[11];

  char* ws = (char*)d_ws;
  float* wts           = (float*)(ws + 0);          // 2048 B
  float* stats         = (float*)(ws + 2048);       // 5120 B (10 slots x 128 f32)
  __hip_bfloat16* wtb  = (__hip_bfloat16*)(ws + 8192);      // 2,654,208 B
  __hip_bfloat16* xpad = (__hip_bfloat16*)(ws + 2662400);   // 34,611,200 B
  __hip_bfloat16* cbuf = (__hip_bfloat16*)(ws + 37273600);  // 33,554,432 B
  float* merged        = (float*)(ws + 70828032);           // 67,108,864 B
  const size_t NEED = 137936896ull;
  if (ws_size < NEED) {  // graceful (wrong-answer) fallback, no corruption
    hipMemsetAsync(d_out, 0, (size_t)out_size * 4, stream);
    return;
  }

  hipMemsetAsync(stats, 0, 5120, stream);
  hipMemsetAsync(xpad, 0, 34611200ull, stream);
  k_router<<<1, 64, 0, stream>>>(router_w, router_b, wts);
  k_build_xpad<<<4096, 256, 0, stream>>>(x, xpad);
  k_build_w<<<4608, 256, 0, stream>>>(expert_w, wtb, 1179648);
  k_build_w<<<576, 256, 0, stream>>>(post_w, wtb + 1179648, 147456);

  for (int e = 0; e < 8; ++e) {
    k_conv<<<1024, 256, 0, stream>>>(xpad, wtb + (size_t)e * 147456, cbuf, stats + e * 128);
    k_merge<<<8192, 256, 0, stream>>>(cbuf, stats + e * 128, expert_g + e * 128,
                                      expert_b + e * 128, wts, merged, e, e > 0 ? 1 : 0);
  }
  k_stats2<<<8192, 256, 0, stream>>>(merged, xpad, stats + 8 * 128);
  k_ypass<<<8192, 256, 0, stream>>>(merged, xpad, stats + 8 * 128, merge_g, merge_b, gamma);
  k_conv<<<1024, 256, 0, stream>>>(xpad, wtb + 1179648, cbuf, stats + 9 * 128);
  k_final<<<2048, 256, 0, stream>>>(cbuf, stats + 9 * 128, post_g, post_b, (float*)d_out);
}